// Round 6
// baseline (226.074 us; speedup 1.0000x reference)
//
#include <hip/hip_runtime.h>
#include <math.h>

#define NN 50000
#define NE 800000
#define HD 128
#define NG 256
#define SCAN_B 196     // ceil(NN/256)
#define XCAST_B 12500  // NN/4
#define HIST_B 3125    // NE/256
#define GEM_B 782      // ceil(NN/64)

typedef unsigned int u32;
typedef unsigned short u16;
typedef __attribute__((ext_vector_type(8))) short bf16x8;
typedef __attribute__((ext_vector_type(4))) float f32x4;

__device__ __forceinline__ float wave_allsum(float v) {
#pragma unroll
  for (int m = 1; m < 64; m <<= 1) v += __shfl_xor(v, m, 64);
  return v;
}
__device__ __forceinline__ float bcastf(float v, int t) {
  return __int_as_float(__builtin_amdgcn_readlane(__float_as_int(v), t));
}
__device__ __forceinline__ u32 f2b_bits(float f) {  // RNE float->bf16 bits
  u32 u = __float_as_uint(f);
  return (u + 0x7fffu + ((u >> 16) & 1u)) >> 16;
}
__device__ __forceinline__ u32 pack2(float lo, float hi) {
  return f2b_bits(lo) | (f2b_bits(hi) << 16);
}

// ---- pack weights to MFMA B-fragment layout (blocks 0..39); block 40 =
//      prevec: vi = pam_w@wi, vj = pam_w@wj, consts, bsum = pam_b + pm_b2 ----
__global__ __launch_bounds__(256) void k_wpack(
    const float* __restrict__ gcn_w, const float* __restrict__ pam_w,
    const float* __restrict__ pm_w2, const float* __restrict__ fus_w,
    const float* __restrict__ pam_b, const float* __restrict__ att_w,
    const float* __restrict__ att_b, const float* __restrict__ pm_b2,
    u16* __restrict__ Bg, u16* __restrict__ Bl, u16* __restrict__ Bf,
    float* __restrict__ vi, float* __restrict__ vj,
    float* __restrict__ consts, float* __restrict__ bsum) {
  if (blockIdx.x == 40) {  // prevec
    const int t = threadIdx.x;
    const int k = t & 127;
    const float* w = att_w + (t >> 7) * HD;
    float s = 0.f;
    for (int h = 0; h < HD; ++h) s = fmaf(pam_w[k * HD + h], w[h], s);
    if (t < 128) {
      vi[k] = s;
      bsum[k] = pam_b[k] + pm_b2[k];
    } else {
      vj[k] = s;
    }
    if (t < 64) {
      float p = fmaf(pam_b[t], att_w[t], pam_b[t + 64] * att_w[t + 64]);
      p = wave_allsum(p);
      if (t == 0) consts[0] = p + att_b[0];
    } else if (t < 128) {
      const int l = t - 64;
      float p =
          fmaf(pam_b[l], att_w[HD + l], pam_b[l + 64] * att_w[HD + 64 + l]);
      p = wave_allsum(p);
      if (l == 0) consts[1] = p;
    }
    return;
  }
  const int t = blockIdx.x * 256 + threadIdx.x;
  const float* W;
  u16* dst;
  if (t < 2048) {  // gcn_w: K=128 -> 16 kb
    const int kb = t >> 7, n = t & 127;
    W = gcn_w + (size_t)kb * 8 * HD + n;
    dst = Bg + (size_t)t * 8;
  } else if (t < 6144) {  // [pam_w; pm_w2]: K=256 -> 32 kb
    const int u = t - 2048;
    const int kb = u >> 7, n = u & 127;
    W = ((kb < 16) ? (pam_w + (size_t)kb * 8 * HD)
                   : (pm_w2 + (size_t)(kb - 16) * 8 * HD)) +
        n;
    dst = Bl + (size_t)u * 8;
  } else {  // fus_w: K=256 -> 32 kb
    const int u = t - 6144;
    const int kb = u >> 7, n = u & 127;
    W = fus_w + (size_t)kb * 8 * HD + n;
    dst = Bf + (size_t)u * 8;
  }
  union {
    u16 o[8];
    uint4 v;
  } pk;
#pragma unroll
  for (int i = 0; i < 8; ++i) pk.o[i] = (u16)f2b_bits(W[i * HD]);
  *(uint4*)dst = pk.v;
}

// ---- merged: x->bf16 + att dots (blocks < XCAST_B) ; degree hist (rest) ----
__global__ __launch_bounds__(256) void k_pre2(
    const float* __restrict__ x, const float* __restrict__ vi,
    const float* __restrict__ vj, const float* __restrict__ consts,
    const int* __restrict__ ei, u32* __restrict__ xb, float* __restrict__ ai,
    float* __restrict__ aj, int* __restrict__ cnt) {
  if (blockIdx.x < XCAST_B) {
    const int wave = threadIdx.x >> 6, lane = threadIdx.x & 63;
    const int i = blockIdx.x * 4 + wave;
    if (i >= NN) return;
    const float2 v = *(const float2*)&x[(size_t)i * HD + lane * 2];
    xb[(size_t)i * 64 + lane] = pack2(v.x, v.y);
    const float2 a = *(const float2*)&vi[lane * 2];
    const float2 b = *(const float2*)&vj[lane * 2];
    float si = wave_allsum(fmaf(v.x, a.x, v.y * a.y));
    float sj = wave_allsum(fmaf(v.x, b.x, v.y * b.y));
    if (lane == 0) {
      ai[i] = si + consts[0];
      aj[i] = sj + consts[1];
    }
  } else {
    const int e = (blockIdx.x - XCAST_B) * 256 + threadIdx.x;
    if (e < NE) atomicAdd(&cnt[ei[NE + e]], 1);
  }
}

// hierarchical scan
__global__ __launch_bounds__(256) void k_scan1(const int* __restrict__ cnt,
                                               int* __restrict__ bsum) {
  const int i = blockIdx.x * 256 + threadIdx.x;
  int v = (i < NN) ? cnt[i] : 0;
#pragma unroll
  for (int m = 1; m < 64; m <<= 1) v += __shfl_xor(v, m, 64);
  __shared__ int s[4];
  if ((threadIdx.x & 63) == 0) s[threadIdx.x >> 6] = v;
  __syncthreads();
  if (threadIdx.x == 0) bsum[blockIdx.x] = s[0] + s[1] + s[2] + s[3];
}

__global__ __launch_bounds__(256) void k_scan2(int* __restrict__ bsum) {
  __shared__ int s[256];
  const int t = threadIdx.x;
  const int v = (t < SCAN_B) ? bsum[t] : 0;
  s[t] = v;
  __syncthreads();
  for (int d = 1; d < 256; d <<= 1) {
    int add = (t >= d) ? s[t - d] : 0;
    __syncthreads();
    s[t] += add;
    __syncthreads();
  }
  if (t < SCAN_B) bsum[t] = s[t] - v;  // exclusive
}

// scan3 + dinv + adj2 (aj,dinv) + pos4 repack
__global__ __launch_bounds__(256) void k_scan3(
    const int* __restrict__ cnt, const int* __restrict__ bsum,
    const float* __restrict__ aj, const float* __restrict__ pos,
    int* __restrict__ offs, float2* __restrict__ adj2,
    float4* __restrict__ pos4) {
  const int t = threadIdx.x;
  const int i = blockIdx.x * 256 + t;
  const int v = (i < NN) ? cnt[i] : 0;
  __shared__ int s[256];
  s[t] = v;
  __syncthreads();
  for (int d = 1; d < 256; d <<= 1) {
    int add = (t >= d) ? s[t - d] : 0;
    __syncthreads();
    s[t] += add;
    __syncthreads();
  }
  if (i < NN) {
    offs[i] = bsum[blockIdx.x] + s[t] - v;
    const float dv = __builtin_amdgcn_rsqf((float)v + 1.0f);
    adj2[i] = make_float2(aj[i], dv);
    pos4[i] = make_float4(pos[3 * i], pos[3 * i + 1], pos[3 * i + 2], 0.f);
  }
}

// ---- merged: CSR scatter (blocks < HIST_B) + graph counts (last block) ----
__global__ __launch_bounds__(256) void k_scatgc(
    const int* __restrict__ ei, const int* __restrict__ offs,
    int* __restrict__ cursor, int* __restrict__ csr_src,
    const int* __restrict__ batch, float* __restrict__ counts) {
  if (blockIdx.x < HIST_B) {
    const int e = blockIdx.x * 256 + threadIdx.x;
    if (e < NE) {
      const int d = ei[NE + e];
      const int slot = atomicAdd(&cursor[d], 1);
      csr_src[offs[d] + slot] = ei[e];
    }
  } else {
    const int g = threadIdx.x;
    int lo = 0, hi = NN;
    while (lo < hi) {
      const int mid = (lo + hi) >> 1;
      if (batch[mid] < g) lo = mid + 1; else hi = mid;
    }
    const int b0 = lo;
    hi = NN;
    while (lo < hi) {
      const int mid = (lo + hi) >> 1;
      if (batch[mid] <= g) lo = mid + 1; else hi = mid;
    }
    counts[g] = (float)(lo - b0);
  }
}

// ---------------- per-node edge aggregation (1 wave / node) ----------------
__global__ __launch_bounds__(256) void k_agg(
    const u32* __restrict__ xb, const float4* __restrict__ pos4,
    const float2* __restrict__ adj2, const int* __restrict__ csr_src,
    const int* __restrict__ offs, const int* __restrict__ cnt,
    const float* __restrict__ ai_arr, const float* __restrict__ pm_w1,
    const float* __restrict__ pm_b1, u32* __restrict__ ZG,
    u32* __restrict__ XT, float* __restrict__ sa_out) {
  const int wave = threadIdx.x >> 6, lane = threadIdx.x & 63;
  const int i = blockIdx.x * 4 + wave;
  if (i >= NN) return;
  const int c0 = lane * 2;

  const float2 w1x = *(const float2*)&pm_w1[c0];
  const float2 w1y = *(const float2*)&pm_w1[HD + c0];
  const float2 w1z = *(const float2*)&pm_w1[2 * HD + c0];
  const float2 b1 = *(const float2*)&pm_b1[c0];
  const float ai = ai_arr[i];
  const float4 pi = pos4[i];
  const float di = adj2[i].y;

  float2 zg = {0.f, 0.f}, xa = {0.f, 0.f}, tt = {0.f, 0.f};
  float sa = 0.f;
  const int b = offs[i], e = b + cnt[i];
  for (int base = b; base < e; base += 64) {
    const int mm = min(64, e - base);
    const int sk = csr_src[base + ((lane < mm) ? lane : 0)];
    const float2 a2 = adj2[sk];  // {aj, dinv}
    float attk = __builtin_amdgcn_rcpf(1.f + __expf(-(ai + a2.x)));
    const float dsk = a2.y;
    const float4 ps = pos4[sk];
    const float dxk = pi.x - ps.x;
    const float dyk = pi.y - ps.y;
    const float dzk = pi.z - ps.z;
    if (lane >= mm) attk = 0.f;
    sa += wave_allsum(attk);

    auto body = [&](int T) {
      const int s = __builtin_amdgcn_readlane(sk, T);
      const float att = bcastf(attk, T);
      const float ds = bcastf(dsk, T);
      const float dx = bcastf(dxk, T);
      const float dy = bcastf(dyk, T);
      const float dz = bcastf(dzk, T);
      const u32 xr = xb[(size_t)s * 64 + lane];
      const float xj0 = __uint_as_float(xr << 16);
      const float xj1 = __uint_as_float(xr & 0xffff0000u);
      zg.x = fmaf(ds, xj0, zg.x);
      zg.y = fmaf(ds, xj1, zg.y);
      xa.x = fmaf(att, xj0, xa.x);
      xa.y = fmaf(att, xj1, xa.y);
      const float g0 =
          fmaxf(fmaf(dz, w1z.x, fmaf(dy, w1y.x, fmaf(dx, w1x.x, b1.x))), 0.f);
      const float g1 =
          fmaxf(fmaf(dz, w1z.y, fmaf(dy, w1y.y, fmaf(dx, w1x.y, b1.y))), 0.f);
      tt.x = fmaf(att, g0, tt.x);
      tt.y = fmaf(att, g1, tt.y);
    };
    int t = 0;
    for (; t + 8 <= mm; t += 8) {
      body(t); body(t + 1); body(t + 2); body(t + 3);
      body(t + 4); body(t + 5); body(t + 6); body(t + 7);
    }
    for (; t + 4 <= mm; t += 4) {
      body(t); body(t + 1); body(t + 2); body(t + 3);
    }
    for (; t < mm; ++t) body(t);
  }
  const u32 xi = xb[(size_t)i * 64 + lane];
  zg.x = fmaf(di, __uint_as_float(xi << 16), zg.x);
  zg.y = fmaf(di, __uint_as_float(xi & 0xffff0000u), zg.y);

  ZG[(size_t)i * 64 + lane] = pack2(zg.x, zg.y);
  XT[(size_t)i * 128 + lane] = pack2(xa.x, xa.y);
  XT[(size_t)i * 128 + 64 + lane] = pack2(tt.x, tt.y);
  if (lane == 0) sa_out[i] = sa;
}

// ---- fused dense tail, 64-row tiles, 4 waves, each wave owns 16 rows.
//      Phases A/B write the wave's own rows to swizzled LDS; phase C reads
//      only those rows back (no barrier needed until pooling). ----
__global__ __launch_bounds__(256, 4) void k_gemms(
    const u16* __restrict__ ZG, const u16* __restrict__ XT,
    const u16* __restrict__ Bg, const u16* __restrict__ Bl,
    const u16* __restrict__ Bf, const float2* __restrict__ adj2,
    const float* __restrict__ sa, const float* __restrict__ gcn_b,
    const float* __restrict__ bsumv, const float* __restrict__ fus_b,
    const int* __restrict__ batch, float* __restrict__ pooled) {
  __shared__ u16 T[64 * 256];  // 32KB bf16 [gl|local]; reused as f32 F[64][128]
  __shared__ int batch_lds[64];
  const int n0 = blockIdx.x * 64;
  const int t = threadIdx.x, lane = t & 63, w = t >> 6;
  const int m = lane & 15, g = lane >> 4;
  const int r0 = w * 16;

  if (t < 64) batch_lds[t] = (n0 + t < NN) ? batch[n0 + t] : -1;

  // ---- all A-fragment loads up-front (12 x 16B in flight) ----
  const int rowA = min(n0 + r0 + m, NN - 1);
  bf16x8 aA[4], aB[8];
  {
    const u16* pa = ZG + (size_t)rowA * 128 + g * 8;
#pragma unroll
    for (int k0 = 0; k0 < 4; ++k0) aA[k0] = *(const bf16x8*)(pa + k0 * 32);
    const u16* pb = XT + (size_t)rowA * 256 + g * 8;
#pragma unroll
    for (int k0 = 0; k0 < 8; ++k0) aB[k0] = *(const bf16x8*)(pb + k0 * 32);
  }

  f32x4 acc[8];
  // ---- phase A: gl = relu(dinv*(ZG@gcn_w) + gcn_b) -> T cols 0..127 ----
#pragma unroll
  for (int cf = 0; cf < 8; ++cf) acc[cf] = (f32x4){0.f, 0.f, 0.f, 0.f};
#pragma unroll
  for (int k0 = 0; k0 < 4; ++k0) {
    const u16* pb = Bg + ((size_t)(g + k0 * 4) * HD + m) * 8;
#pragma unroll
    for (int cf = 0; cf < 8; ++cf)
      acc[cf] = __builtin_amdgcn_mfma_f32_16x16x32_bf16(
          aA[k0], *(const bf16x8*)(pb + cf * 128), acc[cf], 0, 0, 0);
  }
#pragma unroll
  for (int j = 0; j < 4; ++j) {
    const int rl = r0 + g * 4 + j;
    const float dv = adj2[min(n0 + rl, NN - 1)].y;
#pragma unroll
    for (int cf = 0; cf < 8; ++cf) {
      const float v = fmaxf(fmaf(dv, acc[cf][j], gcn_b[cf * 16 + m]), 0.f);
      T[rl * 256 + ((cf * 16 + m) ^ ((rl & 7) << 3))] = (u16)f2b_bits(v);
    }
  }

  // ---- phase B: local = relu(XT@Bl + sa*bsum) -> T cols 128..255 ----
#pragma unroll
  for (int cf = 0; cf < 8; ++cf) acc[cf] = (f32x4){0.f, 0.f, 0.f, 0.f};
#pragma unroll
  for (int k0 = 0; k0 < 8; ++k0) {
    const u16* pb = Bl + ((size_t)(g + k0 * 4) * HD + m) * 8;
#pragma unroll
    for (int cf = 0; cf < 8; ++cf)
      acc[cf] = __builtin_amdgcn_mfma_f32_16x16x32_bf16(
          aB[k0], *(const bf16x8*)(pb + cf * 128), acc[cf], 0, 0, 0);
  }
#pragma unroll
  for (int j = 0; j < 4; ++j) {
    const int rl = r0 + g * 4 + j;
    const float sv = sa[min(n0 + rl, NN - 1)];
#pragma unroll
    for (int cf = 0; cf < 8; ++cf) {
      const float v = fmaxf(fmaf(sv, bsumv[cf * 16 + m], acc[cf][j]), 0.f);
      T[rl * 256 + ((128 + cf * 16 + m) ^ ((rl & 7) << 3))] = (u16)f2b_bits(v);
    }
  }

  // ---- phase C: fused = relu([gl|local]@fus_w + fus_b), A-frags from LDS
  //      (this wave's own rows -> no __syncthreads needed) ----
  bf16x8 aC[8];
#pragma unroll
  for (int k0 = 0; k0 < 8; ++k0)
    aC[k0] = *(const bf16x8*)&T[(r0 + m) * 256 +
                                ((g * 8 + k0 * 32) ^ ((m & 7) << 3))];
#pragma unroll
  for (int cf = 0; cf < 8; ++cf) acc[cf] = (f32x4){0.f, 0.f, 0.f, 0.f};
#pragma unroll
  for (int k0 = 0; k0 < 8; ++k0) {
    const u16* pb = Bf + ((size_t)(g + k0 * 4) * HD + m) * 8;
#pragma unroll
    for (int cf = 0; cf < 8; ++cf)
      acc[cf] = __builtin_amdgcn_mfma_f32_16x16x32_bf16(
          aC[k0], *(const bf16x8*)(pb + cf * 128), acc[cf], 0, 0, 0);
  }
  float* F = (float*)T;  // overwrite own rows only
#pragma unroll
  for (int j = 0; j < 4; ++j) {
    const int rl = r0 + g * 4 + j;
#pragma unroll
    for (int cf = 0; cf < 8; ++cf)
      F[rl * 128 + ((cf * 16 + m) ^ ((rl & 12) << 2))] =
          fmaxf(acc[cf][j] + fus_b[cf * 16 + m], 0.f);
  }
  __syncthreads();

  // ---- segment pooling over sorted batch ids (two 32-row halves) ----
  const int col = t & 127;
  const int q = t >> 7;
  int seg = -1;
  float run = 0.f;
  for (int r = q * 32; r < q * 32 + 32; ++r) {
    const int bg = batch_lds[r];
    const float v = F[r * 128 + (col ^ ((r & 12) << 2))];
    if (bg != seg) {
      if (seg >= 0) atomicAdd(&pooled[seg * HD + col], run);
      seg = bg;
      run = 0.f;
    }
    if (bg >= 0) run += v;
  }
  if (seg >= 0) atomicAdd(&pooled[seg * HD + col], run);
}

// ---------------- head: out = relu(pooled/cnt @ l1)@l2 ----------------
__global__ __launch_bounds__(64) void k_head(const float* __restrict__ pooled,
                                             const float* __restrict__ counts,
                                             const float* __restrict__ l1w,
                                             const float* __restrict__ l1b,
                                             const float* __restrict__ l2w,
                                             const float* __restrict__ l2b,
                                             float* __restrict__ out) {
  const int g = blockIdx.x, j = threadIdx.x;
  const float inv = __builtin_amdgcn_rcpf(fmaxf(counts[g], 1.f));
  float acc = l1b[j];
  for (int k = 0; k < HD; ++k)
    acc = fmaf(pooled[g * HD + k] * inv, l1w[k * 64 + j], acc);
  float v = fmaxf(acc, 0.f) * l2w[j];
  v = wave_allsum(v);
  if (j == 0) out[g] = v + l2b[0];
}

extern "C" void kernel_launch(void* const* d_in, const int* in_sizes, int n_in,
                              void* d_out, int out_size, void* d_ws,
                              size_t ws_size, hipStream_t stream) {
  const float* x = (const float*)d_in[0];
  const float* pos = (const float*)d_in[1];
  const int* ei = (const int*)d_in[2];
  const int* batch = (const int*)d_in[3];
  const float* gcn_w = (const float*)d_in[4];
  const float* gcn_b = (const float*)d_in[5];
  const float* pam_w = (const float*)d_in[6];
  const float* pam_b = (const float*)d_in[7];
  const float* pm_w1 = (const float*)d_in[8];
  const float* pm_b1 = (const float*)d_in[9];
  const float* pm_w2 = (const float*)d_in[10];
  const float* pm_b2 = (const float*)d_in[11];
  const float* att_w = (const float*)d_in[12];
  const float* att_b = (const float*)d_in[13];
  const float* fus_w = (const float*)d_in[14];
  const float* fus_b = (const float*)d_in[15];
  const float* l1_w = (const float*)d_in[16];
  const float* l1_b = (const float*)d_in[17];
  const float* l2_w = (const float*)d_in[18];
  const float* l2_b = (const float*)d_in[19];
  float* out = (float*)d_out;

  size_t off = 0;
  auto alloc = [&](size_t bytes) {
    void* p = (char*)d_ws + off;
    off += (bytes + 255) & ~size_t(255);
    return p;
  };
  u32* xb = (u32*)alloc((size_t)NN * 64 * 4);
  u32* ZG = (u32*)alloc((size_t)NN * 64 * 4);
  u32* XT = (u32*)alloc((size_t)NN * 128 * 4);
  float* sa = (float*)alloc((size_t)NN * 4);
  float* ai = (float*)alloc((size_t)NN * 4);
  float* aj = (float*)alloc((size_t)NN * 4);
  float2* adj2 = (float2*)alloc((size_t)NN * 8);
  float4* pos4 = (float4*)alloc((size_t)NN * 16);
  float* pooled = (float*)alloc((size_t)NG * HD * 4);
  float* counts = (float*)alloc((size_t)NG * 4);
  int* cnt = (int*)alloc((size_t)NN * 4);  // cnt+cursor contiguous: 1 memset
  int* cursor = (int*)alloc((size_t)NN * 4);
  int* offs = (int*)alloc((size_t)NN * 4);
  int* csr_src = (int*)alloc((size_t)NE * 4);
  int* bsum = (int*)alloc((size_t)SCAN_B * 4);
  u16* Bg = (u16*)alloc((size_t)16 * 128 * 8 * 2);
  u16* Bl = (u16*)alloc((size_t)32 * 128 * 8 * 2);
  u16* Bf = (u16*)alloc((size_t)32 * 128 * 8 * 2);
  float* vi = (float*)alloc(128 * 4);
  float* vj = (float*)alloc(128 * 4);
  float* consts = (float*)alloc(2 * 4);
  float* bsumv = (float*)alloc(128 * 4);

  hipMemsetAsync(cnt, 0, ((char*)cursor - (char*)cnt) + NN * 4, stream);
  hipMemsetAsync(pooled, 0, NG * HD * 4, stream);

  k_wpack<<<41, 256, 0, stream>>>(gcn_w, pam_w, pm_w2, fus_w, pam_b, att_w,
                                  att_b, pm_b2, Bg, Bl, Bf, vi, vj, consts,
                                  bsumv);
  k_pre2<<<XCAST_B + HIST_B, 256, 0, stream>>>(x, vi, vj, consts, ei, xb, ai,
                                               aj, cnt);
  k_scan1<<<SCAN_B, 256, 0, stream>>>(cnt, bsum);
  k_scan2<<<1, 256, 0, stream>>>(bsum);
  k_scan3<<<SCAN_B, 256, 0, stream>>>(cnt, bsum, aj, pos, offs, adj2, pos4);
  k_scatgc<<<HIST_B + 1, 256, 0, stream>>>(ei, offs, cursor, csr_src, batch,
                                           counts);
  k_agg<<<XCAST_B, 256, 0, stream>>>(xb, pos4, adj2, csr_src, offs, cnt, ai,
                                     pm_w1, pm_b1, ZG, XT, sa);
  k_gemms<<<GEM_B, 256, 0, stream>>>((const u16*)ZG, (const u16*)XT, Bg, Bl,
                                     Bf, adj2, sa, gcn_b, bsumv, fus_b, batch,
                                     pooled);
  k_head<<<NG, 64, 0, stream>>>(pooled, counts, l1_w, l1_b, l2_w, l2_b, out);
}

// Round 7
// 209.220 us; speedup vs baseline: 1.0806x; 1.0806x over previous
//
#include <hip/hip_runtime.h>
#include <math.h>

#define NN 50000
#define NE 800000
#define HD 128
#define NG 256
#define SCAN_B 196     // ceil(NN/256)
#define NODE_B 12500   // NN/4
#define HIST_B 3125    // NE/256
#define GEM_B 782      // ceil(NN/64)
#define ZQ1 25024      // (2*200192)/16 uint4 for cnt+cursor
#define ZQ2 8192       // 131072/16 uint4 for pooled

typedef unsigned int u32;
typedef unsigned short u16;
typedef __attribute__((ext_vector_type(8))) short bf16x8;
typedef __attribute__((ext_vector_type(4))) float f32x4;

__device__ __forceinline__ float wave_allsum(float v) {
#pragma unroll
  for (int m = 1; m < 64; m <<= 1) v += __shfl_xor(v, m, 64);
  return v;
}
__device__ __forceinline__ float bcastf(float v, int t) {
  return __int_as_float(__builtin_amdgcn_readlane(__float_as_int(v), t));
}
__device__ __forceinline__ u32 f2b_bits(float f) {  // RNE float->bf16 bits
  u32 u = __float_as_uint(f);
  return (u + 0x7fffu + ((u >> 16) & 1u)) >> 16;
}
__device__ __forceinline__ u32 pack2(float lo, float hi) {
  return f2b_bits(lo) | (f2b_bits(hi) << 16);
}

// ---- blocks 0..39: pack weights to MFMA B-frag layout; block 40: prevec;
//      blocks 41..170: zero cnt+cursor and pooled ----
__global__ __launch_bounds__(256) void k_wpack(
    const float* __restrict__ gcn_w, const float* __restrict__ pam_w,
    const float* __restrict__ pm_w2, const float* __restrict__ fus_w,
    const float* __restrict__ pam_b, const float* __restrict__ att_w,
    const float* __restrict__ att_b, const float* __restrict__ pm_b2,
    u16* __restrict__ Bg, u16* __restrict__ Bl, u16* __restrict__ Bf,
    float* __restrict__ vi, float* __restrict__ vj,
    float* __restrict__ consts, float* __restrict__ bsumv,
    uint4* __restrict__ zr1, uint4* __restrict__ zr2) {
  if (blockIdx.x >= 41) {  // zero regions
    int zi = (blockIdx.x - 41) * 256 + threadIdx.x;
    const uint4 z = {0u, 0u, 0u, 0u};
    if (zi < ZQ1) zr1[zi] = z;
    else if ((zi -= ZQ1) < ZQ2) zr2[zi] = z;
    return;
  }
  if (blockIdx.x == 40) {  // prevec
    const int t = threadIdx.x;
    const int k = t & 127;
    const float* w = att_w + (t >> 7) * HD;
    float s = 0.f;
    for (int h = 0; h < HD; ++h) s = fmaf(pam_w[k * HD + h], w[h], s);
    if (t < 128) {
      vi[k] = s;
      bsumv[k] = pam_b[k] + pm_b2[k];
    } else {
      vj[k] = s;
    }
    if (t < 64) {
      float p = fmaf(pam_b[t], att_w[t], pam_b[t + 64] * att_w[t + 64]);
      p = wave_allsum(p);
      if (t == 0) consts[0] = p + att_b[0];
    } else if (t < 128) {
      const int l = t - 64;
      float p =
          fmaf(pam_b[l], att_w[HD + l], pam_b[l + 64] * att_w[HD + 64 + l]);
      p = wave_allsum(p);
      if (l == 0) consts[1] = p;
    }
    return;
  }
  const int t = blockIdx.x * 256 + threadIdx.x;
  const float* W;
  u16* dst;
  if (t < 2048) {  // gcn_w: K=128 -> 16 kb
    const int kb = t >> 7, n = t & 127;
    W = gcn_w + (size_t)kb * 8 * HD + n;
    dst = Bg + (size_t)t * 8;
  } else if (t < 6144) {  // [pam_w; pm_w2]: K=256 -> 32 kb
    const int u = t - 2048;
    const int kb = u >> 7, n = u & 127;
    W = ((kb < 16) ? (pam_w + (size_t)kb * 8 * HD)
                   : (pm_w2 + (size_t)(kb - 16) * 8 * HD)) +
        n;
    dst = Bl + (size_t)u * 8;
  } else {  // fus_w: K=256 -> 32 kb
    const int u = t - 6144;
    const int kb = u >> 7, n = u & 127;
    W = fus_w + (size_t)kb * 8 * HD + n;
    dst = Bf + (size_t)u * 8;
  }
  union {
    u16 o[8];
    uint4 v;
  } pk;
#pragma unroll
  for (int i = 0; i < 8; ++i) pk.o[i] = (u16)f2b_bits(W[i * HD]);
  *(uint4*)dst = pk.v;
}

// ---- degree histogram ----
__global__ __launch_bounds__(256) void k_hist(const int* __restrict__ ei,
                                              int* __restrict__ cnt) {
  int e = blockIdx.x * 256 + threadIdx.x;
  if (e < NE) atomicAdd(&cnt[ei[NE + e]], 1);
}

// ---- per-256-block sums of cnt ----
__global__ __launch_bounds__(256) void k_scan1(const int* __restrict__ cnt,
                                               int* __restrict__ bsum) {
  const int i = blockIdx.x * 256 + threadIdx.x;
  int v = (i < NN) ? cnt[i] : 0;
#pragma unroll
  for (int m = 1; m < 64; m <<= 1) v += __shfl_xor(v, m, 64);
  __shared__ int s[4];
  if ((threadIdx.x & 63) == 0) s[threadIdx.x >> 6] = v;
  __syncthreads();
  if (threadIdx.x == 0) bsum[blockIdx.x] = s[0] + s[1] + s[2] + s[3];
}

// ---- merged scan2+scan3: each block scans bsum itself, then local scan;
//      emits offs, dinv, pos4 ----
__global__ __launch_bounds__(256) void k_scan23(
    const int* __restrict__ cnt, const int* __restrict__ bsum,
    const float* __restrict__ pos, int* __restrict__ offs,
    float* __restrict__ dinv, float4* __restrict__ pos4) {
  __shared__ int s[256];
  const int t = threadIdx.x;
  const int bv = (t < SCAN_B) ? bsum[t] : 0;
  s[t] = bv;
  __syncthreads();
  for (int d = 1; d < 256; d <<= 1) {
    int add = (t >= d) ? s[t - d] : 0;
    __syncthreads();
    s[t] += add;
    __syncthreads();
  }
  const int bpre = (blockIdx.x > 0) ? s[blockIdx.x - 1] : 0;
  __syncthreads();
  const int i = blockIdx.x * 256 + t;
  const int v = (i < NN) ? cnt[i] : 0;
  s[t] = v;
  __syncthreads();
  for (int d = 1; d < 256; d <<= 1) {
    int add = (t >= d) ? s[t - d] : 0;
    __syncthreads();
    s[t] += add;
    __syncthreads();
  }
  if (i < NN) {
    offs[i] = bpre + s[t] - v;
    dinv[i] = __builtin_amdgcn_rsqf((float)v + 1.0f);
    pos4[i] = make_float4(pos[3 * i], pos[3 * i + 1], pos[3 * i + 2], 0.f);
  }
}

// ---- merged: CSR scatter | graph counts | node pass (att dots + y-cast) ----
__global__ __launch_bounds__(256) void k_scatgc(
    const int* __restrict__ ei, const int* __restrict__ offs,
    int* __restrict__ cursor, int* __restrict__ csr_src,
    const int* __restrict__ batch, float* __restrict__ counts,
    const float* __restrict__ x, const float* __restrict__ dinv,
    const int* __restrict__ cnt, const float* __restrict__ vi,
    const float* __restrict__ vj, const float* __restrict__ consts,
    u32* __restrict__ xb, float* __restrict__ ai_arr,
    float2* __restrict__ adj2) {
  if (blockIdx.x < HIST_B) {  // scatter
    const int e = blockIdx.x * 256 + threadIdx.x;
    if (e < NE) {
      const int d = ei[NE + e];
      const int slot = atomicAdd(&cursor[d], 1);
      csr_src[offs[d] + slot] = ei[e];
    }
    return;
  }
  if (blockIdx.x == HIST_B) {  // graph counts via binary search
    const int g = threadIdx.x;
    int lo = 0, hi = NN;
    while (lo < hi) {
      const int mid = (lo + hi) >> 1;
      if (batch[mid] < g) lo = mid + 1; else hi = mid;
    }
    const int b0 = lo;
    hi = NN;
    while (lo < hi) {
      const int mid = (lo + hi) >> 1;
      if (batch[mid] <= g) lo = mid + 1; else hi = mid;
    }
    counts[g] = (float)(lo - b0);
    return;
  }
  // node pass: y = dinv*x (bf16), ai = x.vi + c0, adj2 = {x.vj + c1, sdeg}
  const int wave = threadIdx.x >> 6, lane = threadIdx.x & 63;
  const int i = (blockIdx.x - HIST_B - 1) * 4 + wave;
  if (i >= NN) return;
  const float2 v = *(const float2*)&x[(size_t)i * HD + lane * 2];
  const float dv = dinv[i];
  xb[(size_t)i * 64 + lane] = pack2(dv * v.x, dv * v.y);
  const float2 a = *(const float2*)&vi[lane * 2];
  const float2 b = *(const float2*)&vj[lane * 2];
  float si = wave_allsum(fmaf(v.x, a.x, v.y * a.y));
  float sj = wave_allsum(fmaf(v.x, b.x, v.y * b.y));
  if (lane == 0) {
    ai_arr[i] = si + consts[0];
    adj2[i] = make_float2(sj + consts[1], sqrtf((float)cnt[i] + 1.0f));
  }
}

// ---------------- per-node edge aggregation (1 wave / node) ----------------
// xb holds y_s = dinv_s * x_s (bf16). zg = sum y_s + y_i ; xa = sum att'*y_s
// (att' = att*sdeg_s) ; tt = sum att*relu(W1.delta + b1) ; sa = sum att.
__global__ __launch_bounds__(256) void k_agg(
    const u32* __restrict__ xb, const float4* __restrict__ pos4,
    const float2* __restrict__ adj2, const int* __restrict__ csr_src,
    const int* __restrict__ offs, const int* __restrict__ cnt,
    const float* __restrict__ ai_arr, const float* __restrict__ pm_w1,
    const float* __restrict__ pm_b1, u32* __restrict__ ZG,
    u32* __restrict__ XT, float* __restrict__ sa_out) {
  const int wave = threadIdx.x >> 6, lane = threadIdx.x & 63;
  const int i = blockIdx.x * 4 + wave;
  if (i >= NN) return;
  const int c0 = lane * 2;

  const float2 w1x = *(const float2*)&pm_w1[c0];
  const float2 w1y = *(const float2*)&pm_w1[HD + c0];
  const float2 w1z = *(const float2*)&pm_w1[2 * HD + c0];
  const float2 b1 = *(const float2*)&pm_b1[c0];
  const float ai = ai_arr[i];
  const float4 pi = pos4[i];

  float2 zg = {0.f, 0.f}, xa = {0.f, 0.f}, tt = {0.f, 0.f};
  float sa = 0.f;
  const int b = offs[i], e = b + cnt[i];
  for (int base = b; base < e; base += 64) {
    const int mm = min(64, e - base);
    const int sk = csr_src[base + ((lane < mm) ? lane : 0)];
    const float2 a2 = adj2[sk];  // {aj, sdeg}
    float attk = __builtin_amdgcn_rcpf(1.f + __expf(-(ai + a2.x)));
    const float4 ps = pos4[sk];
    const float apk = attk * a2.y;  // att' = att*sdeg
    const float dxk = pi.x - ps.x;
    const float dyk = pi.y - ps.y;
    const float dzk = pi.z - ps.z;
    if (lane >= mm) attk = 0.f;
    sa += wave_allsum(attk);

    for (int s16 = 0; s16 < mm; s16 += 16) {
      const int n16 = min(16, mm - s16);
      u32 rr[16];
#pragma unroll
      for (int u = 0; u < 16; ++u) {
        if (u < n16) {
          const int s = __builtin_amdgcn_readlane(sk, s16 + u);
          rr[u] = xb[(size_t)s * 64 + lane];
        }
      }
#pragma unroll
      for (int u = 0; u < 16; ++u) {
        if (u < n16) {
          const int T = s16 + u;
          const float att = bcastf(attk, T);
          const float ap = bcastf(apk, T);
          const float dx = bcastf(dxk, T);
          const float dy = bcastf(dyk, T);
          const float dz = bcastf(dzk, T);
          const float y0 = __uint_as_float(rr[u] << 16);
          const float y1 = __uint_as_float(rr[u] & 0xffff0000u);
          zg.x += y0;
          zg.y += y1;
          xa.x = fmaf(ap, y0, xa.x);
          xa.y = fmaf(ap, y1, xa.y);
          const float g0 = fmaxf(
              fmaf(dz, w1z.x, fmaf(dy, w1y.x, fmaf(dx, w1x.x, b1.x))), 0.f);
          const float g1 = fmaxf(
              fmaf(dz, w1z.y, fmaf(dy, w1y.y, fmaf(dx, w1x.y, b1.y))), 0.f);
          tt.x = fmaf(att, g0, tt.x);
          tt.y = fmaf(att, g1, tt.y);
        }
      }
    }
  }
  const u32 xi = xb[(size_t)i * 64 + lane];  // self term: y_i
  zg.x += __uint_as_float(xi << 16);
  zg.y += __uint_as_float(xi & 0xffff0000u);

  ZG[(size_t)i * 64 + lane] = pack2(zg.x, zg.y);
  XT[(size_t)i * 128 + lane] = pack2(xa.x, xa.y);
  XT[(size_t)i * 128 + 64 + lane] = pack2(tt.x, tt.y);
  if (lane == 0) sa_out[i] = sa;
}

// ---- fused dense tail, 64-row tiles, 4 waves, each wave owns 16 rows ----
__global__ __launch_bounds__(256, 4) void k_gemms(
    const u16* __restrict__ ZG, const u16* __restrict__ XT,
    const u16* __restrict__ Bg, const u16* __restrict__ Bl,
    const u16* __restrict__ Bf, const float* __restrict__ dinv,
    const float* __restrict__ sa, const float* __restrict__ gcn_b,
    const float* __restrict__ bsumv, const float* __restrict__ fus_b,
    const int* __restrict__ batch, float* __restrict__ pooled) {
  __shared__ u16 T[64 * 256];  // 32KB bf16 [gl|local]; reused as f32 F[64][128]
  __shared__ int batch_lds[64];
  const int n0 = blockIdx.x * 64;
  const int t = threadIdx.x, lane = t & 63, w = t >> 6;
  const int m = lane & 15, g = lane >> 4;
  const int r0 = w * 16;

  if (t < 64) batch_lds[t] = (n0 + t < NN) ? batch[n0 + t] : -1;

  const int rowA = min(n0 + r0 + m, NN - 1);
  bf16x8 aA[4], aB[8];
  {
    const u16* pa = ZG + (size_t)rowA * 128 + g * 8;
#pragma unroll
    for (int k0 = 0; k0 < 4; ++k0) aA[k0] = *(const bf16x8*)(pa + k0 * 32);
    const u16* pb = XT + (size_t)rowA * 256 + g * 8;
#pragma unroll
    for (int k0 = 0; k0 < 8; ++k0) aB[k0] = *(const bf16x8*)(pb + k0 * 32);
  }

  f32x4 acc[8];
  // ---- phase A: gl = relu(dinv*(ZG@gcn_w) + gcn_b) -> T cols 0..127 ----
#pragma unroll
  for (int cf = 0; cf < 8; ++cf) acc[cf] = (f32x4){0.f, 0.f, 0.f, 0.f};
#pragma unroll
  for (int k0 = 0; k0 < 4; ++k0) {
    const u16* pb = Bg + ((size_t)(g + k0 * 4) * HD + m) * 8;
#pragma unroll
    for (int cf = 0; cf < 8; ++cf)
      acc[cf] = __builtin_amdgcn_mfma_f32_16x16x32_bf16(
          aA[k0], *(const bf16x8*)(pb + cf * 128), acc[cf], 0, 0, 0);
  }
#pragma unroll
  for (int j = 0; j < 4; ++j) {
    const int rl = r0 + g * 4 + j;
    const float dv = dinv[min(n0 + rl, NN - 1)];
#pragma unroll
    for (int cf = 0; cf < 8; ++cf) {
      const float v = fmaxf(fmaf(dv, acc[cf][j], gcn_b[cf * 16 + m]), 0.f);
      T[rl * 256 + ((cf * 16 + m) ^ ((rl & 7) << 3))] = (u16)f2b_bits(v);
    }
  }

  // ---- phase B: local = relu(XT@Bl + sa*bsum) -> T cols 128..255 ----
#pragma unroll
  for (int cf = 0; cf < 8; ++cf) acc[cf] = (f32x4){0.f, 0.f, 0.f, 0.f};
#pragma unroll
  for (int k0 = 0; k0 < 8; ++k0) {
    const u16* pb = Bl + ((size_t)(g + k0 * 4) * HD + m) * 8;
#pragma unroll
    for (int cf = 0; cf < 8; ++cf)
      acc[cf] = __builtin_amdgcn_mfma_f32_16x16x32_bf16(
          aB[k0], *(const bf16x8*)(pb + cf * 128), acc[cf], 0, 0, 0);
  }
#pragma unroll
  for (int j = 0; j < 4; ++j) {
    const int rl = r0 + g * 4 + j;
    const float sv = sa[min(n0 + rl, NN - 1)];
#pragma unroll
    for (int cf = 0; cf < 8; ++cf) {
      const float v = fmaxf(fmaf(sv, bsumv[cf * 16 + m], acc[cf][j]), 0.f);
      T[rl * 256 + ((128 + cf * 16 + m) ^ ((rl & 7) << 3))] = (u16)f2b_bits(v);
    }
  }

  // ---- phase C: fused = relu([gl|local]@fus_w + fus_b) ----
  bf16x8 aC[8];
#pragma unroll
  for (int k0 = 0; k0 < 8; ++k0)
    aC[k0] = *(const bf16x8*)&T[(r0 + m) * 256 +
                                ((g * 8 + k0 * 32) ^ ((m & 7) << 3))];
#pragma unroll
  for (int cf = 0; cf < 8; ++cf) acc[cf] = (f32x4){0.f, 0.f, 0.f, 0.f};
#pragma unroll
  for (int k0 = 0; k0 < 8; ++k0) {
    const u16* pb = Bf + ((size_t)(g + k0 * 4) * HD + m) * 8;
#pragma unroll
    for (int cf = 0; cf < 8; ++cf)
      acc[cf] = __builtin_amdgcn_mfma_f32_16x16x32_bf16(
          aC[k0], *(const bf16x8*)(pb + cf * 128), acc[cf], 0, 0, 0);
  }
  float* F = (float*)T;  // overwrite own rows only
#pragma unroll
  for (int j = 0; j < 4; ++j) {
    const int rl = r0 + g * 4 + j;
#pragma unroll
    for (int cf = 0; cf < 8; ++cf)
      F[rl * 128 + ((cf * 16 + m) ^ ((rl & 12) << 2))] =
          fmaxf(acc[cf][j] + fus_b[cf * 16 + m], 0.f);
  }
  __syncthreads();

  // ---- segment pooling over sorted batch ids ----
  const int col = t & 127;
  const int q = t >> 7;
  int seg = -1;
  float run = 0.f;
  for (int r = q * 32; r < q * 32 + 32; ++r) {
    const int bg = batch_lds[r];
    const float v = F[r * 128 + (col ^ ((r & 12) << 2))];
    if (bg != seg) {
      if (seg >= 0) atomicAdd(&pooled[seg * HD + col], run);
      seg = bg;
      run = 0.f;
    }
    if (bg >= 0) run += v;
  }
  if (seg >= 0) atomicAdd(&pooled[seg * HD + col], run);
}

// ---------------- head: out = relu(pooled/cnt @ l1)@l2 ----------------
__global__ __launch_bounds__(64) void k_head(const float* __restrict__ pooled,
                                             const float* __restrict__ counts,
                                             const float* __restrict__ l1w,
                                             const float* __restrict__ l1b,
                                             const float* __restrict__ l2w,
                                             const float* __restrict__ l2b,
                                             float* __restrict__ out) {
  const int g = blockIdx.x, j = threadIdx.x;
  const float inv = __builtin_amdgcn_rcpf(fmaxf(counts[g], 1.f));
  float acc = l1b[j];
  for (int k = 0; k < HD; ++k)
    acc = fmaf(pooled[g * HD + k] * inv, l1w[k * 64 + j], acc);
  float v = fmaxf(acc, 0.f) * l2w[j];
  v = wave_allsum(v);
  if (j == 0) out[g] = v + l2b[0];
}

extern "C" void kernel_launch(void* const* d_in, const int* in_sizes, int n_in,
                              void* d_out, int out_size, void* d_ws,
                              size_t ws_size, hipStream_t stream) {
  const float* x = (const float*)d_in[0];
  const float* pos = (const float*)d_in[1];
  const int* ei = (const int*)d_in[2];
  const int* batch = (const int*)d_in[3];
  const float* gcn_w = (const float*)d_in[4];
  const float* gcn_b = (const float*)d_in[5];
  const float* pam_w = (const float*)d_in[6];
  const float* pam_b = (const float*)d_in[7];
  const float* pm_w1 = (const float*)d_in[8];
  const float* pm_b1 = (const float*)d_in[9];
  const float* pm_w2 = (const float*)d_in[10];
  const float* pm_b2 = (const float*)d_in[11];
  const float* att_w = (const float*)d_in[12];
  const float* att_b = (const float*)d_in[13];
  const float* fus_w = (const float*)d_in[14];
  const float* fus_b = (const float*)d_in[15];
  const float* l1_w = (const float*)d_in[16];
  const float* l1_b = (const float*)d_in[17];
  const float* l2_w = (const float*)d_in[18];
  const float* l2_b = (const float*)d_in[19];
  float* out = (float*)d_out;

  size_t off = 0;
  auto alloc = [&](size_t bytes) {
    void* p = (char*)d_ws + off;
    off += (bytes + 255) & ~size_t(255);
    return p;
  };
  u32* xb = (u32*)alloc((size_t)NN * 64 * 4);   // y = dinv*x, bf16 pairs
  u32* ZG = (u32*)alloc((size_t)NN * 64 * 4);
  u32* XT = (u32*)alloc((size_t)NN * 128 * 4);
  float* sa = (float*)alloc((size_t)NN * 4);
  float* ai = (float*)alloc((size_t)NN * 4);
  float* dinv = (float*)alloc((size_t)NN * 4);
  float2* adj2 = (float2*)alloc((size_t)NN * 8);  // {aj, sdeg}
  float4* pos4 = (float4*)alloc((size_t)NN * 16);
  float* pooled = (float*)alloc((size_t)NG * HD * 4);
  float* counts = (float*)alloc((size_t)NG * 4);
  int* cnt = (int*)alloc((size_t)NN * 4);  // cnt+cursor contiguous (zeroed)
  int* cursor = (int*)alloc((size_t)NN * 4);
  int* offs = (int*)alloc((size_t)NN * 4);
  int* csr_src = (int*)alloc((size_t)NE * 4);
  int* bsum = (int*)alloc((size_t)SCAN_B * 4);
  u16* Bg = (u16*)alloc((size_t)16 * 128 * 8 * 2);
  u16* Bl = (u16*)alloc((size_t)32 * 128 * 8 * 2);
  u16* Bf = (u16*)alloc((size_t)32 * 128 * 8 * 2);
  float* vi = (float*)alloc(128 * 4);
  float* vj = (float*)alloc(128 * 4);
  float* consts = (float*)alloc(2 * 4);
  float* bsumv = (float*)alloc(128 * 4);

  k_wpack<<<171, 256, 0, stream>>>(gcn_w, pam_w, pm_w2, fus_w, pam_b, att_w,
                                   att_b, pm_b2, Bg, Bl, Bf, vi, vj, consts,
                                   bsumv, (uint4*)cnt, (uint4*)pooled);
  k_hist<<<HIST_B, 256, 0, stream>>>(ei, cnt);
  k_scan1<<<SCAN_B, 256, 0, stream>>>(cnt, bsum);
  k_scan23<<<SCAN_B, 256, 0, stream>>>(cnt, bsum, pos, offs, dinv, pos4);
  k_scatgc<<<HIST_B + 1 + NODE_B, 256, 0, stream>>>(
      ei, offs, cursor, csr_src, batch, counts, x, dinv, cnt, vi, vj, consts,
      xb, ai, adj2);
  k_agg<<<NODE_B, 256, 0, stream>>>(xb, pos4, adj2, csr_src, offs, cnt, ai,
                                    pm_w1, pm_b1, ZG, XT, sa);
  k_gemms<<<GEM_B, 256, 0, stream>>>((const u16*)ZG, (const u16*)XT, Bg, Bl,
                                     Bf, dinv, sa, gcn_b, bsumv, fus_b, batch,
                                     pooled);
  k_head<<<NG, 64, 0, stream>>>(pooled, counts, l1_w, l1_b, l2_w, l2_b, out);
}

// Round 8
// 199.204 us; speedup vs baseline: 1.1349x; 1.0503x over previous
//
#include <hip/hip_runtime.h>
#include <math.h>

#define NN 50000
#define NE 800000
#define HD 128
#define NG 256
#define SCAN_B 196     // ceil(NN/256)
#define NODE_B 12500   // NN/4
#define HIST_B 3125    // NE/256
#define GEM_B 782      // ceil(NN/64)
#define ZQ1 12512      // 200192/16 uint4 for cnt
#define ZQ2 8192       // 131072/16 uint4 for pooled

typedef unsigned int u32;
typedef unsigned short u16;
typedef __attribute__((ext_vector_type(8))) short bf16x8;
typedef __attribute__((ext_vector_type(4))) float f32x4;

__device__ __forceinline__ float wave_allsum(float v) {
#pragma unroll
  for (int m = 1; m < 64; m <<= 1) v += __shfl_xor(v, m, 64);
  return v;
}
__device__ __forceinline__ float bcastf(float v, int t) {
  return __int_as_float(__builtin_amdgcn_readlane(__float_as_int(v), t));
}
__device__ __forceinline__ u32 f2b_bits(float f) {  // RNE float->bf16 bits
  u32 u = __float_as_uint(f);
  return (u + 0x7fffu + ((u >> 16) & 1u)) >> 16;
}
__device__ __forceinline__ u32 pack2(float lo, float hi) {
  return f2b_bits(lo) | (f2b_bits(hi) << 16);
}

// ---- blocks 0..39: pack weights to MFMA B-frag layout; block 40: prevec;
//      blocks 41..: zero cnt and pooled ----
__global__ __launch_bounds__(256) void k_wpack(
    const float* __restrict__ gcn_w, const float* __restrict__ pam_w,
    const float* __restrict__ pm_w2, const float* __restrict__ fus_w,
    const float* __restrict__ pam_b, const float* __restrict__ att_w,
    const float* __restrict__ att_b, const float* __restrict__ pm_b2,
    u16* __restrict__ Bg, u16* __restrict__ Bl, u16* __restrict__ Bf,
    float* __restrict__ vi, float* __restrict__ vj,
    float* __restrict__ consts, float* __restrict__ bsumv,
    uint4* __restrict__ zr1, uint4* __restrict__ zr2) {
  if (blockIdx.x >= 41) {  // zero regions
    int zi = (blockIdx.x - 41) * 256 + threadIdx.x;
    const uint4 z = {0u, 0u, 0u, 0u};
    if (zi < ZQ1) zr1[zi] = z;
    else if ((zi -= ZQ1) < ZQ2) zr2[zi] = z;
    return;
  }
  if (blockIdx.x == 40) {  // prevec
    const int t = threadIdx.x;
    const int k = t & 127;
    const float* w = att_w + (t >> 7) * HD;
    float s = 0.f;
    for (int h = 0; h < HD; ++h) s = fmaf(pam_w[k * HD + h], w[h], s);
    if (t < 128) {
      vi[k] = s;
      bsumv[k] = pam_b[k] + pm_b2[k];
    } else {
      vj[k] = s;
    }
    if (t < 64) {
      float p = fmaf(pam_b[t], att_w[t], pam_b[t + 64] * att_w[t + 64]);
      p = wave_allsum(p);
      if (t == 0) consts[0] = p + att_b[0];
    } else if (t < 128) {
      const int l = t - 64;
      float p =
          fmaf(pam_b[l], att_w[HD + l], pam_b[l + 64] * att_w[HD + 64 + l]);
      p = wave_allsum(p);
      if (l == 0) consts[1] = p;
    }
    return;
  }
  const int t = blockIdx.x * 256 + threadIdx.x;
  const float* W;
  u16* dst;
  if (t < 2048) {  // gcn_w: K=128 -> 16 kb
    const int kb = t >> 7, n = t & 127;
    W = gcn_w + (size_t)kb * 8 * HD + n;
    dst = Bg + (size_t)t * 8;
  } else if (t < 6144) {  // [pam_w; pm_w2]: K=256 -> 32 kb
    const int u = t - 2048;
    const int kb = u >> 7, n = u & 127;
    W = ((kb < 16) ? (pam_w + (size_t)kb * 8 * HD)
                   : (pm_w2 + (size_t)(kb - 16) * 8 * HD)) +
        n;
    dst = Bl + (size_t)u * 8;
  } else {  // fus_w: K=256 -> 32 kb
    const int u = t - 6144;
    const int kb = u >> 7, n = u & 127;
    W = fus_w + (size_t)kb * 8 * HD + n;
    dst = Bf + (size_t)u * 8;
  }
  union {
    u16 o[8];
    uint4 v;
  } pk;
#pragma unroll
  for (int i = 0; i < 8; ++i) pk.o[i] = (u16)f2b_bits(W[i * HD]);
  *(uint4*)dst = pk.v;
}

// ---- degree histogram; the atomic's return value IS the edge's slot ----
__global__ __launch_bounds__(256) void k_hist(const int* __restrict__ ei,
                                              int* __restrict__ cnt,
                                              u16* __restrict__ slot16) {
  int e = blockIdx.x * 256 + threadIdx.x;
  if (e < NE) slot16[e] = (u16)atomicAdd(&cnt[ei[NE + e]], 1);
}

// ---- per-256-block sums of cnt ----
__global__ __launch_bounds__(256) void k_scan1(const int* __restrict__ cnt,
                                               int* __restrict__ bsum) {
  const int i = blockIdx.x * 256 + threadIdx.x;
  int v = (i < NN) ? cnt[i] : 0;
#pragma unroll
  for (int m = 1; m < 64; m <<= 1) v += __shfl_xor(v, m, 64);
  __shared__ int s[4];
  if ((threadIdx.x & 63) == 0) s[threadIdx.x >> 6] = v;
  __syncthreads();
  if (threadIdx.x == 0) bsum[blockIdx.x] = s[0] + s[1] + s[2] + s[3];
}

// ---- merged scan2+scan3: emits offs, dinv, pos4 ----
__global__ __launch_bounds__(256) void k_scan23(
    const int* __restrict__ cnt, const int* __restrict__ bsum,
    const float* __restrict__ pos, int* __restrict__ offs,
    float* __restrict__ dinv, float4* __restrict__ pos4) {
  __shared__ int s[256];
  const int t = threadIdx.x;
  const int bv = (t < SCAN_B) ? bsum[t] : 0;
  s[t] = bv;
  __syncthreads();
  for (int d = 1; d < 256; d <<= 1) {
    int add = (t >= d) ? s[t - d] : 0;
    __syncthreads();
    s[t] += add;
    __syncthreads();
  }
  const int bpre = (blockIdx.x > 0) ? s[blockIdx.x - 1] : 0;
  __syncthreads();
  const int i = blockIdx.x * 256 + t;
  const int v = (i < NN) ? cnt[i] : 0;
  s[t] = v;
  __syncthreads();
  for (int d = 1; d < 256; d <<= 1) {
    int add = (t >= d) ? s[t - d] : 0;
    __syncthreads();
    s[t] += add;
    __syncthreads();
  }
  if (i < NN) {
    offs[i] = bpre + s[t] - v;
    dinv[i] = __builtin_amdgcn_rsqf((float)v + 1.0f);
    pos4[i] = make_float4(pos[3 * i], pos[3 * i + 1], pos[3 * i + 2], 0.f);
  }
}

// ---- merged: CSR scatter (no atomics) | graph counts | node pass ----
__global__ __launch_bounds__(256) void k_scatgc(
    const int* __restrict__ ei, const int* __restrict__ offs,
    const u16* __restrict__ slot16, int* __restrict__ csr_src,
    const int* __restrict__ batch, float* __restrict__ counts,
    const float* __restrict__ x, const float* __restrict__ dinv,
    const int* __restrict__ cnt, const float* __restrict__ vi,
    const float* __restrict__ vj, const float* __restrict__ consts,
    u32* __restrict__ xb, float* __restrict__ ai_arr,
    float2* __restrict__ adj2) {
  if (blockIdx.x < HIST_B) {  // scatter: fire-and-forget stores
    const int e = blockIdx.x * 256 + threadIdx.x;
    if (e < NE) {
      const int d = ei[NE + e];
      __builtin_nontemporal_store(ei[e], &csr_src[offs[d] + slot16[e]]);
    }
    return;
  }
  if (blockIdx.x == HIST_B) {  // graph counts via binary search
    const int g = threadIdx.x;
    int lo = 0, hi = NN;
    while (lo < hi) {
      const int mid = (lo + hi) >> 1;
      if (batch[mid] < g) lo = mid + 1; else hi = mid;
    }
    const int b0 = lo;
    hi = NN;
    while (lo < hi) {
      const int mid = (lo + hi) >> 1;
      if (batch[mid] <= g) lo = mid + 1; else hi = mid;
    }
    counts[g] = (float)(lo - b0);
    return;
  }
  // node pass: y = dinv*x (bf16), ai = x.vi + c0, adj2 = {x.vj + c1, sdeg}
  const int wave = threadIdx.x >> 6, lane = threadIdx.x & 63;
  const int i = (blockIdx.x - HIST_B - 1) * 4 + wave;
  if (i >= NN) return;
  const float2 v = *(const float2*)&x[(size_t)i * HD + lane * 2];
  const float dv = dinv[i];
  xb[(size_t)i * 64 + lane] = pack2(dv * v.x, dv * v.y);
  const float2 a = *(const float2*)&vi[lane * 2];
  const float2 b = *(const float2*)&vj[lane * 2];
  float si = wave_allsum(fmaf(v.x, a.x, v.y * a.y));
  float sj = wave_allsum(fmaf(v.x, b.x, v.y * b.y));
  if (lane == 0) {
    ai_arr[i] = si + consts[0];
    adj2[i] = make_float2(sj + consts[1], sqrtf((float)cnt[i] + 1.0f));
  }
}

// ---------------- per-node edge aggregation (1 wave / node) ----------------
__global__ __launch_bounds__(256) void k_agg(
    const u32* __restrict__ xb, const float4* __restrict__ pos4,
    const float2* __restrict__ adj2, const int* __restrict__ csr_src,
    const int* __restrict__ offs, const int* __restrict__ cnt,
    const float* __restrict__ ai_arr, const float* __restrict__ pm_w1,
    const float* __restrict__ pm_b1, u32* __restrict__ ZG,
    u32* __restrict__ XT, float* __restrict__ sa_out) {
  const int wave = threadIdx.x >> 6, lane = threadIdx.x & 63;
  const int i = blockIdx.x * 4 + wave;
  if (i >= NN) return;
  const int c0 = lane * 2;

  const float2 w1x = *(const float2*)&pm_w1[c0];
  const float2 w1y = *(const float2*)&pm_w1[HD + c0];
  const float2 w1z = *(const float2*)&pm_w1[2 * HD + c0];
  const float2 b1 = *(const float2*)&pm_b1[c0];
  const float ai = ai_arr[i];
  const float4 pi = pos4[i];

  float2 zg = {0.f, 0.f}, xa = {0.f, 0.f}, tt = {0.f, 0.f};
  float sa = 0.f;
  const int b = offs[i], e = b + cnt[i];
  for (int base = b; base < e; base += 64) {
    const int mm = min(64, e - base);
    const int sk = csr_src[base + ((lane < mm) ? lane : 0)];
    const float2 a2 = adj2[sk];  // {aj, sdeg}
    float attk = __builtin_amdgcn_rcpf(1.f + __expf(-(ai + a2.x)));
    const float4 ps = pos4[sk];
    const float apk = attk * a2.y;  // att' = att*sdeg
    const float dxk = pi.x - ps.x;
    const float dyk = pi.y - ps.y;
    const float dzk = pi.z - ps.z;
    if (lane >= mm) attk = 0.f;
    sa += wave_allsum(attk);

    for (int s16 = 0; s16 < mm; s16 += 16) {
      const int n16 = min(16, mm - s16);
      u32 rr[16];
#pragma unroll
      for (int u = 0; u < 16; ++u) {
        if (u < n16) {
          const int s = __builtin_amdgcn_readlane(sk, s16 + u);
          rr[u] = xb[(size_t)s * 64 + lane];
        }
      }
#pragma unroll
      for (int u = 0; u < 16; ++u) {
        if (u < n16) {
          const int T = s16 + u;
          const float att = bcastf(attk, T);
          const float ap = bcastf(apk, T);
          const float dx = bcastf(dxk, T);
          const float dy = bcastf(dyk, T);
          const float dz = bcastf(dzk, T);
          const float y0 = __uint_as_float(rr[u] << 16);
          const float y1 = __uint_as_float(rr[u] & 0xffff0000u);
          zg.x += y0;
          zg.y += y1;
          xa.x = fmaf(ap, y0, xa.x);
          xa.y = fmaf(ap, y1, xa.y);
          const float g0 = fmaxf(
              fmaf(dz, w1z.x, fmaf(dy, w1y.x, fmaf(dx, w1x.x, b1.x))), 0.f);
          const float g1 = fmaxf(
              fmaf(dz, w1z.y, fmaf(dy, w1y.y, fmaf(dx, w1x.y, b1.y))), 0.f);
          tt.x = fmaf(att, g0, tt.x);
          tt.y = fmaf(att, g1, tt.y);
        }
      }
    }
  }
  const u32 xi = xb[(size_t)i * 64 + lane];  // self term: y_i
  zg.x += __uint_as_float(xi << 16);
  zg.y += __uint_as_float(xi & 0xffff0000u);

  ZG[(size_t)i * 64 + lane] = pack2(zg.x, zg.y);
  XT[(size_t)i * 128 + lane] = pack2(xa.x, xa.y);
  XT[(size_t)i * 128 + 64 + lane] = pack2(tt.x, tt.y);
  if (lane == 0) sa_out[i] = sa;
}

// ---- fused dense tail, 64-row tiles, 4 waves, each wave owns 16 rows ----
__global__ __launch_bounds__(256, 4) void k_gemms(
    const u16* __restrict__ ZG, const u16* __restrict__ XT,
    const u16* __restrict__ Bg, const u16* __restrict__ Bl,
    const u16* __restrict__ Bf, const float* __restrict__ dinv,
    const float* __restrict__ sa, const float* __restrict__ gcn_b,
    const float* __restrict__ bsumv, const float* __restrict__ fus_b,
    const int* __restrict__ batch, float* __restrict__ pooled) {
  __shared__ u16 T[64 * 256];  // 32KB bf16 [gl|local]; reused as f32 F[64][128]
  __shared__ int batch_lds[64];
  const int n0 = blockIdx.x * 64;
  const int t = threadIdx.x, lane = t & 63, w = t >> 6;
  const int m = lane & 15, g = lane >> 4;
  const int r0 = w * 16;

  if (t < 64) batch_lds[t] = (n0 + t < NN) ? batch[n0 + t] : -1;

  const int rowA = min(n0 + r0 + m, NN - 1);
  bf16x8 aA[4], aB[8];
  {
    const u16* pa = ZG + (size_t)rowA * 128 + g * 8;
#pragma unroll
    for (int k0 = 0; k0 < 4; ++k0) aA[k0] = *(const bf16x8*)(pa + k0 * 32);
    const u16* pb = XT + (size_t)rowA * 256 + g * 8;
#pragma unroll
    for (int k0 = 0; k0 < 8; ++k0) aB[k0] = *(const bf16x8*)(pb + k0 * 32);
  }

  f32x4 acc[8];
  // ---- phase A: gl = relu(dinv*(ZG@gcn_w) + gcn_b) -> T cols 0..127 ----
#pragma unroll
  for (int cf = 0; cf < 8; ++cf) acc[cf] = (f32x4){0.f, 0.f, 0.f, 0.f};
#pragma unroll
  for (int k0 = 0; k0 < 4; ++k0) {
    const u16* pb = Bg + ((size_t)(g + k0 * 4) * HD + m) * 8;
#pragma unroll
    for (int cf = 0; cf < 8; ++cf)
      acc[cf] = __builtin_amdgcn_mfma_f32_16x16x32_bf16(
          aA[k0], *(const bf16x8*)(pb + cf * 128), acc[cf], 0, 0, 0);
  }
#pragma unroll
  for (int j = 0; j < 4; ++j) {
    const int rl = r0 + g * 4 + j;
    const float dv = dinv[min(n0 + rl, NN - 1)];
#pragma unroll
    for (int cf = 0; cf < 8; ++cf) {
      const float v = fmaxf(fmaf(dv, acc[cf][j], gcn_b[cf * 16 + m]), 0.f);
      T[rl * 256 + ((cf * 16 + m) ^ ((rl & 7) << 3))] = (u16)f2b_bits(v);
    }
  }

  // ---- phase B: local = relu(XT@Bl + sa*bsum) -> T cols 128..255 ----
#pragma unroll
  for (int cf = 0; cf < 8; ++cf) acc[cf] = (f32x4){0.f, 0.f, 0.f, 0.f};
#pragma unroll
  for (int k0 = 0; k0 < 8; ++k0) {
    const u16* pb = Bl + ((size_t)(g + k0 * 4) * HD + m) * 8;
#pragma unroll
    for (int cf = 0; cf < 8; ++cf)
      acc[cf] = __builtin_amdgcn_mfma_f32_16x16x32_bf16(
          aB[k0], *(const bf16x8*)(pb + cf * 128), acc[cf], 0, 0, 0);
  }
#pragma unroll
  for (int j = 0; j < 4; ++j) {
    const int rl = r0 + g * 4 + j;
    const float sv = sa[min(n0 + rl, NN - 1)];
#pragma unroll
    for (int cf = 0; cf < 8; ++cf) {
      const float v = fmaxf(fmaf(sv, bsumv[cf * 16 + m], acc[cf][j]), 0.f);
      T[rl * 256 + ((128 + cf * 16 + m) ^ ((rl & 7) << 3))] = (u16)f2b_bits(v);
    }
  }

  // ---- phase C: fused = relu([gl|local]@fus_w + fus_b) ----
  bf16x8 aC[8];
#pragma unroll
  for (int k0 = 0; k0 < 8; ++k0)
    aC[k0] = *(const bf16x8*)&T[(r0 + m) * 256 +
                                ((g * 8 + k0 * 32) ^ ((m & 7) << 3))];
#pragma unroll
  for (int cf = 0; cf < 8; ++cf) acc[cf] = (f32x4){0.f, 0.f, 0.f, 0.f};
#pragma unroll
  for (int k0 = 0; k0 < 8; ++k0) {
    const u16* pb = Bf + ((size_t)(g + k0 * 4) * HD + m) * 8;
#pragma unroll
    for (int cf = 0; cf < 8; ++cf)
      acc[cf] = __builtin_amdgcn_mfma_f32_16x16x32_bf16(
          aC[k0], *(const bf16x8*)(pb + cf * 128), acc[cf], 0, 0, 0);
  }
  float* F = (float*)T;  // overwrite own rows only
#pragma unroll
  for (int j = 0; j < 4; ++j) {
    const int rl = r0 + g * 4 + j;
#pragma unroll
    for (int cf = 0; cf < 8; ++cf)
      F[rl * 128 + ((cf * 16 + m) ^ ((rl & 12) << 2))] =
          fmaxf(acc[cf][j] + fus_b[cf * 16 + m], 0.f);
  }
  __syncthreads();

  // ---- segment pooling over sorted batch ids ----
  const int col = t & 127;
  const int q = t >> 7;
  int seg = -1;
  float run = 0.f;
  for (int r = q * 32; r < q * 32 + 32; ++r) {
    const int bg = batch_lds[r];
    const float v = F[r * 128 + (col ^ ((r & 12) << 2))];
    if (bg != seg) {
      if (seg >= 0) atomicAdd(&pooled[seg * HD + col], run);
      seg = bg;
      run = 0.f;
    }
    if (bg >= 0) run += v;
  }
  if (seg >= 0) atomicAdd(&pooled[seg * HD + col], run);
}

// ---------------- head: out = relu(pooled/cnt @ l1)@l2 ----------------
__global__ __launch_bounds__(64) void k_head(const float* __restrict__ pooled,
                                             const float* __restrict__ counts,
                                             const float* __restrict__ l1w,
                                             const float* __restrict__ l1b,
                                             const float* __restrict__ l2w,
                                             const float* __restrict__ l2b,
                                             float* __restrict__ out) {
  const int g = blockIdx.x, j = threadIdx.x;
  const float inv = __builtin_amdgcn_rcpf(fmaxf(counts[g], 1.f));
  float acc = l1b[j];
  for (int k = 0; k < HD; ++k)
    acc = fmaf(pooled[g * HD + k] * inv, l1w[k * 64 + j], acc);
  float v = fmaxf(acc, 0.f) * l2w[j];
  v = wave_allsum(v);
  if (j == 0) out[g] = v + l2b[0];
}

extern "C" void kernel_launch(void* const* d_in, const int* in_sizes, int n_in,
                              void* d_out, int out_size, void* d_ws,
                              size_t ws_size, hipStream_t stream) {
  const float* x = (const float*)d_in[0];
  const float* pos = (const float*)d_in[1];
  const int* ei = (const int*)d_in[2];
  const int* batch = (const int*)d_in[3];
  const float* gcn_w = (const float*)d_in[4];
  const float* gcn_b = (const float*)d_in[5];
  const float* pam_w = (const float*)d_in[6];
  const float* pam_b = (const float*)d_in[7];
  const float* pm_w1 = (const float*)d_in[8];
  const float* pm_b1 = (const float*)d_in[9];
  const float* pm_w2 = (const float*)d_in[10];
  const float* pm_b2 = (const float*)d_in[11];
  const float* att_w = (const float*)d_in[12];
  const float* att_b = (const float*)d_in[13];
  const float* fus_w = (const float*)d_in[14];
  const float* fus_b = (const float*)d_in[15];
  const float* l1_w = (const float*)d_in[16];
  const float* l1_b = (const float*)d_in[17];
  const float* l2_w = (const float*)d_in[18];
  const float* l2_b = (const float*)d_in[19];
  float* out = (float*)d_out;

  size_t off = 0;
  auto alloc = [&](size_t bytes) {
    void* p = (char*)d_ws + off;
    off += (bytes + 255) & ~size_t(255);
    return p;
  };
  u32* xb = (u32*)alloc((size_t)NN * 64 * 4);   // y = dinv*x, bf16 pairs
  u32* ZG = (u32*)alloc((size_t)NN * 64 * 4);
  u32* XT = (u32*)alloc((size_t)NN * 128 * 4);
  float* sa = (float*)alloc((size_t)NN * 4);
  float* ai = (float*)alloc((size_t)NN * 4);
  float* dinv = (float*)alloc((size_t)NN * 4);
  float2* adj2 = (float2*)alloc((size_t)NN * 8);  // {aj, sdeg}
  float4* pos4 = (float4*)alloc((size_t)NN * 16);
  float* pooled = (float*)alloc((size_t)NG * HD * 4);
  float* counts = (float*)alloc((size_t)NG * 4);
  int* cnt = (int*)alloc((size_t)NN * 4);  // zeroed in k_wpack
  int* offs = (int*)alloc((size_t)NN * 4);
  int* csr_src = (int*)alloc((size_t)NE * 4);
  u16* slot16 = (u16*)alloc((size_t)NE * 2);
  int* bsum = (int*)alloc((size_t)SCAN_B * 4);
  u16* Bg = (u16*)alloc((size_t)16 * 128 * 8 * 2);
  u16* Bl = (u16*)alloc((size_t)32 * 128 * 8 * 2);
  u16* Bf = (u16*)alloc((size_t)32 * 128 * 8 * 2);
  float* vi = (float*)alloc(128 * 4);
  float* vj = (float*)alloc(128 * 4);
  float* consts = (float*)alloc(2 * 4);
  float* bsumv = (float*)alloc(128 * 4);

  k_wpack<<<41 + (ZQ1 + ZQ2 + 255) / 256, 256, 0, stream>>>(
      gcn_w, pam_w, pm_w2, fus_w, pam_b, att_w, att_b, pm_b2, Bg, Bl, Bf, vi,
      vj, consts, bsumv, (uint4*)cnt, (uint4*)pooled);
  k_hist<<<HIST_B, 256, 0, stream>>>(ei, cnt, slot16);
  k_scan1<<<SCAN_B, 256, 0, stream>>>(cnt, bsum);
  k_scan23<<<SCAN_B, 256, 0, stream>>>(cnt, bsum, pos, offs, dinv, pos4);
  k_scatgc<<<HIST_B + 1 + NODE_B, 256, 0, stream>>>(
      ei, offs, slot16, csr_src, batch, counts, x, dinv, cnt, vi, vj, consts,
      xb, ai, adj2);
  k_agg<<<NODE_B, 256, 0, stream>>>(xb, pos4, adj2, csr_src, offs, cnt, ai,
                                    pm_w1, pm_b1, ZG, XT, sa);
  k_gemms<<<GEM_B, 256, 0, stream>>>((const u16*)ZG, (const u16*)XT, Bg, Bl,
                                     Bf, dinv, sa, gcn_b, bsumv, fus_b, batch,
                                     pooled);
  k_head<<<NG, 64, 0, stream>>>(pooled, counts, l1_w, l1_b, l2_w, l2_b, out);
}

// Round 9
// 178.362 us; speedup vs baseline: 1.2675x; 1.1169x over previous
//
#include <hip/hip_runtime.h>
#include <math.h>

#define NN 50000
#define NE 800000
#define HD 128
#define NG 256
#define SCAN_B 196     // ceil(NN/256)
#define NODE_B 12500   // NN/4
#define HIST_B 3125    // NE/256
#define GEM_B 782      // ceil(NN/64)
#define ZQ1 12512      // 200192/16 uint4 for cnt
#define ZQ2 8192       // 131072/16 uint4 for pooled

typedef unsigned int u32;
typedef unsigned short u16;
typedef __attribute__((ext_vector_type(8))) short bf16x8;
typedef __attribute__((ext_vector_type(4))) float f32x4;

__device__ __forceinline__ float wave_allsum(float v) {
#pragma unroll
  for (int m = 1; m < 64; m <<= 1) v += __shfl_xor(v, m, 64);
  return v;
}
__device__ __forceinline__ float bcastf(float v, int t) {
  return __int_as_float(__builtin_amdgcn_readlane(__float_as_int(v), t));
}
__device__ __forceinline__ u32 f2b_bits(float f) {  // RNE float->bf16 bits
  u32 u = __float_as_uint(f);
  return (u + 0x7fffu + ((u >> 16) & 1u)) >> 16;
}
__device__ __forceinline__ u32 pack2(float lo, float hi) {
  return f2b_bits(lo) | (f2b_bits(hi) << 16);
}

// ---- blocks 0..39: pack weights to MFMA B-frag layout; block 40: prevec;
//      blocks 41..: zero cnt and pooled ----
__global__ __launch_bounds__(256) void k_wpack(
    const float* __restrict__ gcn_w, const float* __restrict__ pam_w,
    const float* __restrict__ pm_w2, const float* __restrict__ fus_w,
    const float* __restrict__ pam_b, const float* __restrict__ att_w,
    const float* __restrict__ att_b, const float* __restrict__ pm_b2,
    u16* __restrict__ Bg, u16* __restrict__ Bl, u16* __restrict__ Bf,
    float* __restrict__ vi, float* __restrict__ vj,
    float* __restrict__ consts, float* __restrict__ bsumv,
    uint4* __restrict__ zr1, uint4* __restrict__ zr2) {
  if (blockIdx.x >= 41) {  // zero regions
    int zi = (blockIdx.x - 41) * 256 + threadIdx.x;
    const uint4 z = {0u, 0u, 0u, 0u};
    if (zi < ZQ1) zr1[zi] = z;
    else if ((zi -= ZQ1) < ZQ2) zr2[zi] = z;
    return;
  }
  if (blockIdx.x == 40) {  // prevec
    const int t = threadIdx.x;
    const int k = t & 127;
    const float* w = att_w + (t >> 7) * HD;
    float s = 0.f;
    for (int h = 0; h < HD; ++h) s = fmaf(pam_w[k * HD + h], w[h], s);
    if (t < 128) {
      vi[k] = s;
      bsumv[k] = pam_b[k] + pm_b2[k];
    } else {
      vj[k] = s;
    }
    if (t < 64) {
      float p = fmaf(pam_b[t], att_w[t], pam_b[t + 64] * att_w[t + 64]);
      p = wave_allsum(p);
      if (t == 0) consts[0] = p + att_b[0];
    } else if (t < 128) {
      const int l = t - 64;
      float p =
          fmaf(pam_b[l], att_w[HD + l], pam_b[l + 64] * att_w[HD + 64 + l]);
      p = wave_allsum(p);
      if (l == 0) consts[1] = p;
    }
    return;
  }
  const int t = blockIdx.x * 256 + threadIdx.x;
  const float* W;
  u16* dst;
  if (t < 2048) {  // gcn_w: K=128 -> 16 kb
    const int kb = t >> 7, n = t & 127;
    W = gcn_w + (size_t)kb * 8 * HD + n;
    dst = Bg + (size_t)t * 8;
  } else if (t < 6144) {  // [pam_w; pm_w2]: K=256 -> 32 kb
    const int u = t - 2048;
    const int kb = u >> 7, n = u & 127;
    W = ((kb < 16) ? (pam_w + (size_t)kb * 8 * HD)
                   : (pm_w2 + (size_t)(kb - 16) * 8 * HD)) +
        n;
    dst = Bl + (size_t)u * 8;
  } else {  // fus_w: K=256 -> 32 kb
    const int u = t - 6144;
    const int kb = u >> 7, n = u & 127;
    W = fus_w + (size_t)kb * 8 * HD + n;
    dst = Bf + (size_t)u * 8;
  }
  union {
    u16 o[8];
    uint4 v;
  } pk;
#pragma unroll
  for (int i = 0; i < 8; ++i) pk.o[i] = (u16)f2b_bits(W[i * HD]);
  *(uint4*)dst = pk.v;
}

// ---- degree histogram; the atomic's return value IS the edge's slot ----
__global__ __launch_bounds__(256) void k_hist(const int* __restrict__ ei,
                                              int* __restrict__ cnt,
                                              u16* __restrict__ slot16) {
  int e = blockIdx.x * 256 + threadIdx.x;
  if (e < NE) slot16[e] = (u16)atomicAdd(&cnt[ei[NE + e]], 1);
}

// ---- per-256-block sums of cnt ----
__global__ __launch_bounds__(256) void k_scan1(const int* __restrict__ cnt,
                                               int* __restrict__ bsum) {
  const int i = blockIdx.x * 256 + threadIdx.x;
  int v = (i < NN) ? cnt[i] : 0;
#pragma unroll
  for (int m = 1; m < 64; m <<= 1) v += __shfl_xor(v, m, 64);
  __shared__ int s[4];
  if ((threadIdx.x & 63) == 0) s[threadIdx.x >> 6] = v;
  __syncthreads();
  if (threadIdx.x == 0) bsum[blockIdx.x] = s[0] + s[1] + s[2] + s[3];
}

// ---- merged scan2+scan3: emits offs, dinv, pos4 ----
__global__ __launch_bounds__(256) void k_scan23(
    const int* __restrict__ cnt, const int* __restrict__ bsum,
    const float* __restrict__ pos, int* __restrict__ offs,
    float* __restrict__ dinv, float4* __restrict__ pos4) {
  __shared__ int s[256];
  const int t = threadIdx.x;
  const int bv = (t < SCAN_B) ? bsum[t] : 0;
  s[t] = bv;
  __syncthreads();
  for (int d = 1; d < 256; d <<= 1) {
    int add = (t >= d) ? s[t - d] : 0;
    __syncthreads();
    s[t] += add;
    __syncthreads();
  }
  const int bpre = (blockIdx.x > 0) ? s[blockIdx.x - 1] : 0;
  __syncthreads();
  const int i = blockIdx.x * 256 + t;
  const int v = (i < NN) ? cnt[i] : 0;
  s[t] = v;
  __syncthreads();
  for (int d = 1; d < 256; d <<= 1) {
    int add = (t >= d) ? s[t - d] : 0;
    __syncthreads();
    s[t] += add;
    __syncthreads();
  }
  if (i < NN) {
    offs[i] = bpre + s[t] - v;
    dinv[i] = __builtin_amdgcn_rsqf((float)v + 1.0f);
    pos4[i] = make_float4(pos[3 * i], pos[3 * i + 1], pos[3 * i + 2], 0.f);
  }
}

// ---- merged: CSR scatter (no atomics) | graph counts | node pass ----
__global__ __launch_bounds__(256) void k_scatgc(
    const int* __restrict__ ei, const int* __restrict__ offs,
    const u16* __restrict__ slot16, int* __restrict__ csr_src,
    const int* __restrict__ batch, float* __restrict__ counts,
    const float* __restrict__ x, const float* __restrict__ dinv,
    const int* __restrict__ cnt, const float* __restrict__ vi,
    const float* __restrict__ vj, const float* __restrict__ consts,
    u32* __restrict__ xb, float* __restrict__ ai_arr,
    float2* __restrict__ adj2) {
  if (blockIdx.x < HIST_B) {  // scatter: fire-and-forget stores
    const int e = blockIdx.x * 256 + threadIdx.x;
    if (e < NE) {
      const int d = ei[NE + e];
      __builtin_nontemporal_store(ei[e], &csr_src[offs[d] + slot16[e]]);
    }
    return;
  }
  if (blockIdx.x == HIST_B) {  // graph counts via binary search
    const int g = threadIdx.x;
    int lo = 0, hi = NN;
    while (lo < hi) {
      const int mid = (lo + hi) >> 1;
      if (batch[mid] < g) lo = mid + 1; else hi = mid;
    }
    const int b0 = lo;
    hi = NN;
    while (lo < hi) {
      const int mid = (lo + hi) >> 1;
      if (batch[mid] <= g) lo = mid + 1; else hi = mid;
    }
    counts[g] = (float)(lo - b0);
    return;
  }
  // node pass: y = dinv*x (bf16), ai = x.vi + c0, adj2 = {x.vj + c1, sdeg}
  const int wave = threadIdx.x >> 6, lane = threadIdx.x & 63;
  const int i = (blockIdx.x - HIST_B - 1) * 4 + wave;
  if (i >= NN) return;
  const float2 v = *(const float2*)&x[(size_t)i * HD + lane * 2];
  const float dv = dinv[i];
  xb[(size_t)i * 64 + lane] = pack2(dv * v.x, dv * v.y);
  const float2 a = *(const float2*)&vi[lane * 2];
  const float2 b = *(const float2*)&vj[lane * 2];
  float si = wave_allsum(fmaf(v.x, a.x, v.y * a.y));
  float sj = wave_allsum(fmaf(v.x, b.x, v.y * b.y));
  if (lane == 0) {
    ai_arr[i] = si + consts[0];
    adj2[i] = make_float2(sj + consts[1], sqrtf((float)cnt[i] + 1.0f));
  }
}

// ---------------- per-node edge aggregation (1 wave / node) ----------------
__global__ __launch_bounds__(256) void k_agg(
    const u32* __restrict__ xb, const float4* __restrict__ pos4,
    const float2* __restrict__ adj2, const int* __restrict__ csr_src,
    const int* __restrict__ offs, const int* __restrict__ cnt,
    const float* __restrict__ ai_arr, const float* __restrict__ pm_w1,
    const float* __restrict__ pm_b1, u32* __restrict__ ZG,
    u32* __restrict__ XT, float* __restrict__ sa_out) {
  const int wave = threadIdx.x >> 6, lane = threadIdx.x & 63;
  const int i = blockIdx.x * 4 + wave;
  if (i >= NN) return;
  const int c0 = lane * 2;

  const float2 w1x = *(const float2*)&pm_w1[c0];
  const float2 w1y = *(const float2*)&pm_w1[HD + c0];
  const float2 w1z = *(const float2*)&pm_w1[2 * HD + c0];
  const float2 b1 = *(const float2*)&pm_b1[c0];
  const float ai = ai_arr[i];
  const float4 pi = pos4[i];

  float2 zg = {0.f, 0.f}, xa = {0.f, 0.f}, tt = {0.f, 0.f};
  float sa = 0.f;
  const int b = offs[i], e = b + cnt[i];
  for (int base = b; base < e; base += 64) {
    const int mm = min(64, e - base);
    const int sk = csr_src[base + ((lane < mm) ? lane : 0)];
    const float2 a2 = adj2[sk];  // {aj, sdeg}
    float attk = __builtin_amdgcn_rcpf(1.f + __expf(-(ai + a2.x)));
    const float4 ps = pos4[sk];
    const float apk = attk * a2.y;  // att' = att*sdeg
    const float dxk = pi.x - ps.x;
    const float dyk = pi.y - ps.y;
    const float dzk = pi.z - ps.z;
    if (lane >= mm) attk = 0.f;
    sa += wave_allsum(attk);

    for (int s16 = 0; s16 < mm; s16 += 16) {
      const int n16 = min(16, mm - s16);
      u32 rr[16];
#pragma unroll
      for (int u = 0; u < 16; ++u) {
        if (u < n16) {
          const int s = __builtin_amdgcn_readlane(sk, s16 + u);
          rr[u] = xb[(size_t)s * 64 + lane];
        }
      }
#pragma unroll
      for (int u = 0; u < 16; ++u) {
        if (u < n16) {
          const int T = s16 + u;
          const float att = bcastf(attk, T);
          const float ap = bcastf(apk, T);
          const float dx = bcastf(dxk, T);
          const float dy = bcastf(dyk, T);
          const float dz = bcastf(dzk, T);
          const float y0 = __uint_as_float(rr[u] << 16);
          const float y1 = __uint_as_float(rr[u] & 0xffff0000u);
          zg.x += y0;
          zg.y += y1;
          xa.x = fmaf(ap, y0, xa.x);
          xa.y = fmaf(ap, y1, xa.y);
          const float g0 = fmaxf(
              fmaf(dz, w1z.x, fmaf(dy, w1y.x, fmaf(dx, w1x.x, b1.x))), 0.f);
          const float g1 = fmaxf(
              fmaf(dz, w1z.y, fmaf(dy, w1y.y, fmaf(dx, w1x.y, b1.y))), 0.f);
          tt.x = fmaf(att, g0, tt.x);
          tt.y = fmaf(att, g1, tt.y);
        }
      }
    }
  }
  const u32 xi = xb[(size_t)i * 64 + lane];  // self term: y_i
  zg.x += __uint_as_float(xi << 16);
  zg.y += __uint_as_float(xi & 0xffff0000u);

  ZG[(size_t)i * 64 + lane] = pack2(zg.x, zg.y);
  XT[(size_t)i * 128 + lane] = pack2(xa.x, xa.y);
  XT[(size_t)i * 128 + 64 + lane] = pack2(tt.x, tt.y);
  if (lane == 0) sa_out[i] = sa;
}

// ---- GEMM phase with double-buffered A (global) and B fragments.
//      9 loads for k0+1 issued before the 8 MFMAs of k0 -> counted vmcnt. ----
template <int K16>
__device__ __forceinline__ void phase_g(const u16* __restrict__ pa,
                                        const u16* __restrict__ pb0,
                                        f32x4 acc[8]) {
  bf16x8 a[2], b[2][8];
  a[0] = *(const bf16x8*)pa;
#pragma unroll
  for (int cf = 0; cf < 8; ++cf) b[0][cf] = *(const bf16x8*)(pb0 + cf * 128);
#pragma unroll
  for (int k0 = 0; k0 < K16; ++k0) {
    if (k0 + 1 < K16) {
      a[(k0 + 1) & 1] = *(const bf16x8*)(pa + (k0 + 1) * 32);
      const u16* pn = pb0 + (size_t)(k0 + 1) * 4096;
#pragma unroll
      for (int cf = 0; cf < 8; ++cf)
        b[(k0 + 1) & 1][cf] = *(const bf16x8*)(pn + cf * 128);
    }
#pragma unroll
    for (int cf = 0; cf < 8; ++cf)
      acc[cf] = __builtin_amdgcn_mfma_f32_16x16x32_bf16(
          a[k0 & 1], b[k0 & 1][cf], acc[cf], 0, 0, 0);
  }
}

// ---- fused dense tail, 64-row tiles, 4 waves, each wave owns 16 rows ----
__global__ __launch_bounds__(256, 3) void k_gemms(
    const u16* __restrict__ ZG, const u16* __restrict__ XT,
    const u16* __restrict__ Bg, const u16* __restrict__ Bl,
    const u16* __restrict__ Bf, const float* __restrict__ dinv,
    const float* __restrict__ sa, const float* __restrict__ gcn_b,
    const float* __restrict__ bsumv, const float* __restrict__ fus_b,
    const int* __restrict__ batch, float* __restrict__ pooled) {
  __shared__ u16 T[64 * 256];  // 32KB bf16 [gl|local]; reused as f32 F[64][128]
  __shared__ int batch_lds[64];
  const int n0 = blockIdx.x * 64;
  const int t = threadIdx.x, lane = t & 63, w = t >> 6;
  const int m = lane & 15, g = lane >> 4;
  const int r0 = w * 16;

  if (t < 64) batch_lds[t] = (n0 + t < NN) ? batch[n0 + t] : -1;

  // hoist epilogue scalars (independent loads, issued early)
  float dv[4], sv[4];
#pragma unroll
  for (int j = 0; j < 4; ++j) {
    const int rr = min(n0 + r0 + g * 4 + j, NN - 1);
    dv[j] = dinv[rr];
    sv[j] = sa[rr];
  }
  float bgv[8], bsv[8];
#pragma unroll
  for (int cf = 0; cf < 8; ++cf) {
    bgv[cf] = gcn_b[cf * 16 + m];
    bsv[cf] = bsumv[cf * 16 + m];
  }

  const int rowA = min(n0 + r0 + m, NN - 1);
  f32x4 acc[8];

  // ---- phase A: gl = relu(dinv*(ZG@gcn_w) + gcn_b) -> T cols 0..127 ----
#pragma unroll
  for (int cf = 0; cf < 8; ++cf) acc[cf] = (f32x4){0.f, 0.f, 0.f, 0.f};
  phase_g<4>(ZG + (size_t)rowA * 128 + g * 8, Bg + ((size_t)g * HD + m) * 8,
             acc);
#pragma unroll
  for (int j = 0; j < 4; ++j) {
    const int rl = r0 + g * 4 + j;
#pragma unroll
    for (int cf = 0; cf < 8; ++cf) {
      const float v = fmaxf(fmaf(dv[j], acc[cf][j], bgv[cf]), 0.f);
      T[rl * 256 + ((cf * 16 + m) ^ ((rl & 7) << 3))] = (u16)f2b_bits(v);
    }
  }

  // ---- phase B: local = relu(XT@Bl + sa*bsum) -> T cols 128..255 ----
#pragma unroll
  for (int cf = 0; cf < 8; ++cf) acc[cf] = (f32x4){0.f, 0.f, 0.f, 0.f};
  phase_g<8>(XT + (size_t)rowA * 256 + g * 8, Bl + ((size_t)g * HD + m) * 8,
             acc);
#pragma unroll
  for (int j = 0; j < 4; ++j) {
    const int rl = r0 + g * 4 + j;
#pragma unroll
    for (int cf = 0; cf < 8; ++cf) {
      const float v = fmaxf(fmaf(sv[j], bsv[cf], acc[cf][j]), 0.f);
      T[rl * 256 + ((128 + cf * 16 + m) ^ ((rl & 7) << 3))] = (u16)f2b_bits(v);
    }
  }

  // ---- phase C: fused = relu([gl|local]@fus_w + fus_b), A from LDS (own
  //      rows; no barrier needed), double-buffered B ----
  const int x0m = (m & 7) << 3;
  const u16* rowT = &T[(r0 + m) * 256];
  const u16* pbC = Bf + ((size_t)g * HD + m) * 8;
#pragma unroll
  for (int cf = 0; cf < 8; ++cf) acc[cf] = (f32x4){0.f, 0.f, 0.f, 0.f};
  {
    bf16x8 a[2], b[2][8];
    a[0] = *(const bf16x8*)&rowT[(g * 8) ^ x0m];
#pragma unroll
    for (int cf = 0; cf < 8; ++cf) b[0][cf] = *(const bf16x8*)(pbC + cf * 128);
#pragma unroll
    for (int k0 = 0; k0 < 8; ++k0) {
      if (k0 + 1 < 8) {
        a[(k0 + 1) & 1] = *(const bf16x8*)&rowT[(g * 8 + (k0 + 1) * 32) ^ x0m];
        const u16* pn = pbC + (size_t)(k0 + 1) * 4096;
#pragma unroll
        for (int cf = 0; cf < 8; ++cf)
          b[(k0 + 1) & 1][cf] = *(const bf16x8*)(pn + cf * 128);
      }
#pragma unroll
      for (int cf = 0; cf < 8; ++cf)
        acc[cf] = __builtin_amdgcn_mfma_f32_16x16x32_bf16(
            a[k0 & 1], b[k0 & 1][cf], acc[cf], 0, 0, 0);
    }
  }
  float* F = (float*)T;  // overwrite own rows only
#pragma unroll
  for (int j = 0; j < 4; ++j) {
    const int rl = r0 + g * 4 + j;
#pragma unroll
    for (int cf = 0; cf < 8; ++cf)
      F[rl * 128 + ((cf * 16 + m) ^ ((rl & 12) << 2))] =
          fmaxf(acc[cf][j] + fus_b[cf * 16 + m], 0.f);
  }
  __syncthreads();

  // ---- segment pooling over sorted batch ids ----
  const int col = t & 127;
  const int q = t >> 7;
  int seg = -1;
  float run = 0.f;
  for (int r = q * 32; r < q * 32 + 32; ++r) {
    const int bg = batch_lds[r];
    const float v = F[r * 128 + (col ^ ((r & 12) << 2))];
    if (bg != seg) {
      if (seg >= 0) atomicAdd(&pooled[seg * HD + col], run);
      seg = bg;
      run = 0.f;
    }
    if (bg >= 0) run += v;
  }
  if (seg >= 0) atomicAdd(&pooled[seg * HD + col], run);
}

// ---------------- head: out = relu(pooled/cnt @ l1)@l2 ----------------
__global__ __launch_bounds__(64) void k_head(const float* __restrict__ pooled,
                                             const float* __restrict__ counts,
                                             const float* __restrict__ l1w,
                                             const float* __restrict__ l1b,
                                             const float* __restrict__ l2w,
                                             const float* __restrict__ l2b,
                                             float* __restrict__ out) {
  const int g = blockIdx.x, j = threadIdx.x;
  const float inv = __builtin_amdgcn_rcpf(fmaxf(counts[g], 1.f));
  float acc = l1b[j];
  for (int k = 0; k < HD; ++k)
    acc = fmaf(pooled[g * HD + k] * inv, l1w[k * 64 + j], acc);
  float v = fmaxf(acc, 0.f) * l2w[j];
  v = wave_allsum(v);
  if (j == 0) out[g] = v + l2b[0];
}

extern "C" void kernel_launch(void* const* d_in, const int* in_sizes, int n_in,
                              void* d_out, int out_size, void* d_ws,
                              size_t ws_size, hipStream_t stream) {
  const float* x = (const float*)d_in[0];
  const float* pos = (const float*)d_in[1];
  const int* ei = (const int*)d_in[2];
  const int* batch = (const int*)d_in[3];
  const float* gcn_w = (const float*)d_in[4];
  const float* gcn_b = (const float*)d_in[5];
  const float* pam_w = (const float*)d_in[6];
  const float* pam_b = (const float*)d_in[7];
  const float* pm_w1 = (const float*)d_in[8];
  const float* pm_b1 = (const float*)d_in[9];
  const float* pm_w2 = (const float*)d_in[10];
  const float* pm_b2 = (const float*)d_in[11];
  const float* att_w = (const float*)d_in[12];
  const float* att_b = (const float*)d_in[13];
  const float* fus_w = (const float*)d_in[14];
  const float* fus_b = (const float*)d_in[15];
  const float* l1_w = (const float*)d_in[16];
  const float* l1_b = (const float*)d_in[17];
  const float* l2_w = (const float*)d_in[18];
  const float* l2_b = (const float*)d_in[19];
  float* out = (float*)d_out;

  size_t off = 0;
  auto alloc = [&](size_t bytes) {
    void* p = (char*)d_ws + off;
    off += (bytes + 255) & ~size_t(255);
    return p;
  };
  u32* xb = (u32*)alloc((size_t)NN * 64 * 4);   // y = dinv*x, bf16 pairs
  u32* ZG = (u32*)alloc((size_t)NN * 64 * 4);
  u32* XT = (u32*)alloc((size_t)NN * 128 * 4);
  float* sa = (float*)alloc((size_t)NN * 4);
  float* ai = (float*)alloc((size_t)NN * 4);
  float* dinv = (float*)alloc((size_t)NN * 4);
  float2* adj2 = (float2*)alloc((size_t)NN * 8);  // {aj, sdeg}
  float4* pos4 = (float4*)alloc((size_t)NN * 16);
  float* pooled = (float*)alloc((size_t)NG * HD * 4);
  float* counts = (float*)alloc((size_t)NG * 4);
  int* cnt = (int*)alloc((size_t)NN * 4);  // zeroed in k_wpack
  int* offs = (int*)alloc((size_t)NN * 4);
  int* csr_src = (int*)alloc((size_t)NE * 4);
  u16* slot16 = (u16*)alloc((size_t)NE * 2);
  int* bsum = (int*)alloc((size_t)SCAN_B * 4);
  u16* Bg = (u16*)alloc((size_t)16 * 128 * 8 * 2);
  u16* Bl = (u16*)alloc((size_t)32 * 128 * 8 * 2);
  u16* Bf = (u16*)alloc((size_t)32 * 128 * 8 * 2);
  float* vi = (float*)alloc(128 * 4);
  float* vj = (float*)alloc(128 * 4);
  float* consts = (float*)alloc(2 * 4);
  float* bsumv = (float*)alloc(128 * 4);

  k_wpack<<<41 + (ZQ1 + ZQ2 + 255) / 256, 256, 0, stream>>>(
      gcn_w, pam_w, pm_w2, fus_w, pam_b, att_w, att_b, pm_b2, Bg, Bl, Bf, vi,
      vj, consts, bsumv, (uint4*)cnt, (uint4*)pooled);
  k_hist<<<HIST_B, 256, 0, stream>>>(ei, cnt, slot16);
  k_scan1<<<SCAN_B, 256, 0, stream>>>(cnt, bsum);
  k_scan23<<<SCAN_B, 256, 0, stream>>>(cnt, bsum, pos, offs, dinv, pos4);
  k_scatgc<<<HIST_B + 1 + NODE_B, 256, 0, stream>>>(
      ei, offs, slot16, csr_src, batch, counts, x, dinv, cnt, vi, vj, consts,
      xb, ai, adj2);
  k_agg<<<NODE_B, 256, 0, stream>>>(xb, pos4, adj2, csr_src, offs, cnt, ai,
                                    pm_w1, pm_b1, ZG, XT, sa);
  k_gemms<<<GEM_B, 256, 0, stream>>>((const u16*)ZG, (const u16*)XT, Bg, Bl,
                                     Bf, dinv, sa, gcn_b, bsumv, fus_b, batch,
                                     pooled);
  k_head<<<NG, 64, 0, stream>>>(pooled, counts, l1_w, l1_b, l2_w, l2_b, out);
}